// Round 6
// baseline (374.219 us; speedup 1.0000x reference)
//
#include <hip/hip_runtime.h>
#include <cstdint>

#define DIM_ 768
#define H_ 6
#define HD_ 128
#define NB_ 4
#define SEQ_ 2048
#define TOK_ (NB_*SEQ_)
#define OUT3_ (3*DIM_)
#define L2E 1.4426950408889634f

typedef __bf16 bf16;
typedef __bf16 bf16x4 __attribute__((ext_vector_type(4)));
typedef __bf16 bf16x8 __attribute__((ext_vector_type(8)));
typedef float f32x4 __attribute__((ext_vector_type(4)));
typedef float f32x16 __attribute__((ext_vector_type(16)));
typedef unsigned int u32;
typedef u32 u32x4 __attribute__((ext_vector_type(4)));

__device__ __forceinline__ void gload16(const void* g, void* lds) {
  __builtin_amdgcn_global_load_lds((const __attribute__((address_space(1))) void*)g,
                                   (__attribute__((address_space(3))) void*)lds,
                                   16, 0, 0);
}

// ---------------- fp32 -> bf16 convert ----------------
__global__ void convert_kernel(const float* __restrict__ in, bf16* __restrict__ out, int n) {
  int i = (blockIdx.x * 256 + threadIdx.x) * 4;
  if (i >= n) return;
  float4 v = *reinterpret_cast<const float4*>(in + i);
  bf16x4 o = { (bf16)v.x, (bf16)v.y, (bf16)v.z, (bf16)v.w };
  *reinterpret_cast<bf16x4*>(out + i) = o;
}

// ---------------- mask kernel ----------------
__global__ void mask_kernel(const float* __restrict__ latency,
                            const float* __restrict__ rw,
                            const float* __restrict__ rb,
                            const float* __restrict__ g1,
                            const float* __restrict__ g2,
                            float* __restrict__ mask6) {
  int i = threadIdx.x;
  if (i < 6) {
    int j = (i < 4) ? 0 : (i - 3);
    float logit = rw[j] * latency[0] + rb[j];
    float z = (logit + g1[j] - g2[j]) / 5.0f;
    float ys = 1.0f / (1.0f + expf(-z));
    float yh = ys > 0.5f ? 1.0f : 0.0f;
    mask6[i] = (yh - ys) + ys;
  }
}

// ---------------- QKV GEMM (bf16 MFMA): qkv = x @ qkv_w^T + b ----------------
// q (scaled by 1/sqrt(d)*log2e) -> [bh][n][d], k -> [bh][n][d], v -> [bh][d][n]
__global__ __launch_bounds__(256)
void qkv_gemm(const bf16* __restrict__ A, const bf16* __restrict__ W,
              const float* __restrict__ bias,
              bf16* __restrict__ q, bf16* __restrict__ k, bf16* __restrict__ vt) {
  __shared__ bf16 As[128 * 32];
  __shared__ bf16 Bs[128 * 32];
  const int tid = threadIdx.x;
  const int l = tid & 63, w = tid >> 6;
  const int lr = l & 15, lg = l >> 4;
  const int wm = w >> 1, wn = w & 1;
  const int tm = blockIdx.y * 128;
  const int on = blockIdx.x * 128;

  f32x4 acc[4][4];
#pragma unroll
  for (int i = 0; i < 4; ++i)
#pragma unroll
    for (int j = 0; j < 4; ++j) acc[i][j] = f32x4{0.f, 0.f, 0.f, 0.f};

  for (int k0 = 0; k0 < DIM_; k0 += 32) {
    __syncthreads();
#pragma unroll
    for (int u = 0; u < 2; ++u) {
      int row = w * 32 + u * 16 + (l >> 2);
      int cb = l & 3;
      gload16(A + (size_t)(tm + row) * DIM_ + k0 + cb * 8, As + (w * 32 + u * 16) * 32);
      gload16(W + (size_t)(on + row) * DIM_ + k0 + cb * 8, Bs + (w * 32 + u * 16) * 32);
    }
    __syncthreads();
    bf16x8 af[4], bfr[4];
#pragma unroll
    for (int i = 0; i < 4; ++i)
      af[i] = *reinterpret_cast<const bf16x8*>(As + (wm * 64 + i * 16 + lr) * 32 + lg * 8);
#pragma unroll
    for (int j = 0; j < 4; ++j)
      bfr[j] = *reinterpret_cast<const bf16x8*>(Bs + (wn * 64 + j * 16 + lr) * 32 + lg * 8);
#pragma unroll
    for (int i = 0; i < 4; ++i)
#pragma unroll
      for (int j = 0; j < 4; ++j)
        acc[i][j] = __builtin_amdgcn_mfma_f32_16x16x32_bf16(af[i], bfr[j], acc[i][j], 0, 0, 0);
  }

  if (on < 2 * DIM_) {
    const int s = on / DIM_;
    const float scale = 0.08838834764831845f * L2E;
#pragma unroll
    for (int i = 0; i < 4; ++i) {
      int t = tm + wm * 64 + i * 16 + lg * 4;
#pragma unroll
      for (int j = 0; j < 4; ++j) {
        int o = on + wn * 64 + j * 16 + lr;
        int rem = o - s * DIM_;
        int hh = rem >> 7, d = rem & 127;
        float bia = bias[o];
#pragma unroll
        for (int r = 0; r < 4; ++r) {
          int tt = t + r;
          int bb = tt >> 11, n = tt & 2047;
          float val = acc[i][j][r] + bia;
          if (s == 0)
            q[((size_t)(bb * H_ + hh) * SEQ_ + n) * HD_ + d] = (bf16)(val * scale);
          else
            k[((size_t)(bb * H_ + hh) * SEQ_ + n) * HD_ + d] = (bf16)val;
        }
      }
    }
  } else {
    // v: transpose 128x128 tile through LDS, write [bh][d][n] coalesced
    const int hh = (on - 2 * DIM_) >> 7;
    const int bb = tm >> 11, n0 = tm & 2047;
    bf16(*Ts)[136] = reinterpret_cast<bf16(*)[136]>(As);
    for (int wc = 0; wc < 2; ++wc) {
#pragma unroll
      for (int j = 0; j < 4; ++j) {
        __syncthreads();
        if (wn == wc) {
          float bia = bias[on + wc * 64 + j * 16 + lr];
#pragma unroll
          for (int i = 0; i < 4; ++i) {
            bf16x4 pk;
#pragma unroll
            for (int r = 0; r < 4; ++r) pk[r] = (bf16)(acc[i][j][r] + bia);
            *reinterpret_cast<bf16x4*>(&Ts[lr][wm * 64 + i * 16 + lg * 4]) = pk;
          }
        }
        __syncthreads();
        int row = tid >> 4;
        int c8 = (tid & 15) * 8;
        bf16x8 v8 = *reinterpret_cast<const bf16x8*>(&Ts[row][c8]);
        int d = wc * 64 + j * 16 + row;
        *reinterpret_cast<bf16x8*>(
            vt + ((size_t)(bb * H_ + hh) * HD_ + d) * SEQ_ + n0 + c8) = v8;
      }
    }
  }
}

// ---------------- proj GEMM (bf16 MFMA): out = ab @ proj_w^T + b (fp32 out) ----------------
__global__ __launch_bounds__(256)
void proj_gemm(const bf16* __restrict__ A, const bf16* __restrict__ W,
               const float* __restrict__ bias, float* __restrict__ out) {
  __shared__ bf16 As[128 * 32];
  __shared__ bf16 Bs[128 * 32];
  const int tid = threadIdx.x;
  const int l = tid & 63, w = tid >> 6;
  const int lr = l & 15, lg = l >> 4;
  const int wm = w >> 1, wn = w & 1;
  const int tm = blockIdx.y * 128;
  const int on = blockIdx.x * 128;

  f32x4 acc[4][4];
#pragma unroll
  for (int i = 0; i < 4; ++i)
#pragma unroll
    for (int j = 0; j < 4; ++j) acc[i][j] = f32x4{0.f, 0.f, 0.f, 0.f};

  for (int k0 = 0; k0 < DIM_; k0 += 32) {
    __syncthreads();
#pragma unroll
    for (int u = 0; u < 2; ++u) {
      int row = w * 32 + u * 16 + (l >> 2);
      int cb = l & 3;
      gload16(A + (size_t)(tm + row) * DIM_ + k0 + cb * 8, As + (w * 32 + u * 16) * 32);
      gload16(W + (size_t)(on + row) * DIM_ + k0 + cb * 8, Bs + (w * 32 + u * 16) * 32);
    }
    __syncthreads();
    bf16x8 af[4], bfr[4];
#pragma unroll
    for (int i = 0; i < 4; ++i)
      af[i] = *reinterpret_cast<const bf16x8*>(As + (wm * 64 + i * 16 + lr) * 32 + lg * 8);
#pragma unroll
    for (int j = 0; j < 4; ++j)
      bfr[j] = *reinterpret_cast<const bf16x8*>(Bs + (wn * 64 + j * 16 + lr) * 32 + lg * 8);
#pragma unroll
    for (int i = 0; i < 4; ++i)
#pragma unroll
      for (int j = 0; j < 4; ++j)
        acc[i][j] = __builtin_amdgcn_mfma_f32_16x16x32_bf16(af[i], bfr[j], acc[i][j], 0, 0, 0);
  }

#pragma unroll
  for (int i = 0; i < 4; ++i) {
#pragma unroll
    for (int j = 0; j < 4; ++j) {
      int o = on + wn * 64 + j * 16 + lr;
      float bia = bias[o];
#pragma unroll
      for (int r = 0; r < 4; ++r) {
        int t = tm + wm * 64 + i * 16 + lg * 4 + r;
        out[(size_t)t * DIM_ + o] = acc[i][j][r] + bia;
      }
    }
  }
}

// ---------------- flash attention, 32x32x16 MFMA, no LDS / no barriers ----------------
// 1 wave per block, QBLK=32, KVBLK=64; K/V read directly from global (L2-resident).
// grid = 24 bh x 64 qtiles = 1536 blocks = exactly 6 per CU.
__global__ __launch_bounds__(64)
void attn_kernel(const bf16* __restrict__ qb, const bf16* __restrict__ kb,
                 const bf16* __restrict__ vtb, const float* __restrict__ mask6,
                 bf16* __restrict__ ab) {
  const int l = threadIdx.x & 63;
  const int kl = l & 31;
  const int hi = l >> 5;
  const int bid = blockIdx.x;
  const int bh = bid % 24;         // all q-tiles of a head on one XCD class
  const int qt = bid / 24;
  const int h = bh % H_;
  const int b = bh / H_;
  const int q0 = qt * 32;

  const bf16* qg = qb + (size_t)bh * SEQ_ * HD_;
  const bf16* kg = kb + (size_t)bh * SEQ_ * HD_;
  const bf16* vg = vtb + (size_t)bh * HD_ * SEQ_;

  // Q B-fragments in regs: lane (q=kl, hi) holds Q[q][kc*16 + hi*8 .. +7]
  bf16x8 qf[8];
#pragma unroll
  for (int kc = 0; kc < 8; ++kc)
    qf[kc] = *reinterpret_cast<const bf16x8*>(
        qg + (size_t)(q0 + kl) * HD_ + kc * 16 + hi * 8);

  f32x16 oacc[4];
#pragma unroll
  for (int df = 0; df < 4; ++df)
#pragma unroll
    for (int r = 0; r < 16; ++r) oacc[df][r] = 0.f;
  float m_lane = -3.0e38f;   // running max for q-row = kl (log2 units)
  float lsum = 0.f;          // per-half-wave partial row sum (merged in epilogue)

  for (int j0 = 0; j0 < SEQ_; j0 += 64) {
    // S^T = K Q^T : A-frag = K rows direct from global (L2 hit)
    f32x16 sacc[2];
#pragma unroll
    for (int kf = 0; kf < 2; ++kf)
#pragma unroll
      for (int r = 0; r < 16; ++r) sacc[kf][r] = 0.f;
    __builtin_amdgcn_s_setprio(1);
#pragma unroll
    for (int kc = 0; kc < 8; ++kc)
#pragma unroll
      for (int kf = 0; kf < 2; ++kf) {
        bf16x8 kfr = *reinterpret_cast<const bf16x8*>(
            kg + (size_t)(j0 + kf * 32 + kl) * HD_ + kc * 16 + hi * 8);
        sacc[kf] = __builtin_amdgcn_mfma_f32_32x32x16_bf16(kfr, qf[kc], sacc[kf], 0, 0, 0);
      }
    __builtin_amdgcn_s_setprio(0);

    // lane-local online softmax for q-row = kl
    float t = sacc[0][0];
#pragma unroll
    for (int kf = 0; kf < 2; ++kf)
#pragma unroll
      for (int r = 0; r < 16; ++r) t = fmaxf(t, sacc[kf][r]);
    t = fmaxf(t, __shfl_xor(t, 32));
    bool need = t > m_lane + 8.0f;  // defer-max (P bounded by 2^8)
    if (__ballot(need) != 0ull) {
      float nm = fmaxf(m_lane, t);
      float c = exp2f(m_lane - nm);
      m_lane = nm;
      lsum *= c;
#pragma unroll
      for (int r = 0; r < 16; ++r) {
        float cr = __shfl(c, (r & 3) + 8 * (r >> 2) + 4 * hi);
#pragma unroll
        for (int df = 0; df < 4; ++df) oacc[df][r] *= cr;
      }
    }

    // P = exp2(S - m) -> bf16 pairs pp[frag][8]
    u32 pp[2][8];
#pragma unroll
    for (int kf = 0; kf < 2; ++kf)
#pragma unroll
      for (int m = 0; m < 8; ++m) {
        float e0 = exp2f(sacc[kf][2 * m] - m_lane);
        float e1 = exp2f(sacc[kf][2 * m + 1] - m_lane);
        lsum += e0 + e1;
        union { u32 u; bf16 hh2[2]; } pk;
        pk.hh2[0] = (bf16)e0; pk.hh2[1] = (bf16)e1;
        pp[kf][m] = pk.u;
      }

    // A-fragments for PV via permlane32_swap (8 swaps)
    u32x4 afv[4];
#pragma unroll
    for (int ks = 0; ks < 4; ++ks) {
      int f = ks >> 1, k2 = ks & 1;
#pragma unroll
      for (int i = 0; i < 2; ++i) {
        u32 a = pp[f][4 * k2 + i];
        u32 b2 = pp[f][4 * k2 + 2 + i];
        asm volatile("v_permlane32_swap_b32 %0, %1" : "+v"(a), "+v"(b2));
        afv[ks][i] = a;
        afv[ks][2 + i] = b2;
      }
    }

    // PV: oacc[q][d] += P[q][key] V[key][d]; B-frag = Vt rows direct from global
    __builtin_amdgcn_s_setprio(1);
#pragma unroll
    for (int df = 0; df < 4; ++df) {
      int d = df * 32 + kl;
#pragma unroll
      for (int ks = 0; ks < 4; ++ks) {
        bf16x8 vf = *reinterpret_cast<const bf16x8*>(
            vg + (size_t)d * SEQ_ + j0 + ks * 16 + hi * 8);
        bf16x8 pa = __builtin_bit_cast(bf16x8, afv[ks]);
        oacc[df] = __builtin_amdgcn_mfma_f32_32x32x16_bf16(pa, vf, oacc[df], 0, 0, 0);
      }
    }
    __builtin_amdgcn_s_setprio(0);
  }

  // epilogue: merge half-wave sums, normalize, head mask, write bf16 [t][c]
  float lt = lsum + __shfl_xor(lsum, 32);
  float hm = mask6[h];
  float inv_l = hm / lt;           // valid for q-row = kl at this lane
#pragma unroll
  for (int r = 0; r < 16; ++r) {
    int qloc = (r & 3) + 8 * (r >> 2) + 4 * hi;
    float invr = __shfl(inv_l, qloc);
    int n = q0 + qloc;
#pragma unroll
    for (int df = 0; df < 4; ++df) {
      int d = df * 32 + kl;
      ab[((size_t)b * SEQ_ + n) * DIM_ + h * HD_ + d] = (bf16)(oacc[df][r] * invr);
    }
  }
}

extern "C" void kernel_launch(void* const* d_in, const int* in_sizes, int n_in,
                              void* d_out, int out_size, void* d_ws, size_t ws_size,
                              hipStream_t stream) {
  const float* x        = (const float*)d_in[0];
  const float* latency  = (const float*)d_in[1];
  const float* qkv_w    = (const float*)d_in[2];
  const float* qkv_b    = (const float*)d_in[3];
  const float* proj_w   = (const float*)d_in[4];
  const float* proj_b   = (const float*)d_in[5];
  const float* router_w = (const float*)d_in[6];
  const float* router_b = (const float*)d_in[7];
  const float* g1       = (const float*)d_in[8];
  const float* g2       = (const float*)d_in[9];
  float* out = (float*)d_out;

  const size_t N_X  = (size_t)TOK_ * DIM_;
  const size_t N_WQ = (size_t)OUT3_ * DIM_;
  const size_t N_WP = (size_t)DIM_ * DIM_;
  const size_t N_P  = (size_t)NB_ * H_ * SEQ_ * HD_;

  float* maskp = (float*)d_ws;
  bf16* xb  = (bf16*)((char*)d_ws + 256);
  bf16* wqb = xb + N_X;
  bf16* wpb = wqb + N_WQ;
  bf16* qbf = wpb + N_WP;
  bf16* kbf = qbf + N_P;
  bf16* vtb = kbf + N_P;
  bf16* abf = vtb + N_P;

  size_t need = 256 + 2 * (N_X + N_WQ + N_WP + 4 * N_P);
  if (ws_size < need) return;

  convert_kernel<<<(int)(N_X / 1024), 256, 0, stream>>>(x, xb, (int)N_X);
  convert_kernel<<<(int)(N_WQ / 1024), 256, 0, stream>>>(qkv_w, wqb, (int)N_WQ);
  convert_kernel<<<(int)(N_WP / 1024), 256, 0, stream>>>(proj_w, wpb, (int)N_WP);
  mask_kernel<<<1, 64, 0, stream>>>(latency, router_w, router_b, g1, g2, maskp);

  qkv_gemm<<<dim3(OUT3_ / 128, TOK_ / 128), 256, 0, stream>>>(xb, wqb, qkv_b, qbf, kbf, vtb);
  attn_kernel<<<dim3(24 * (SEQ_ / 32)), 64, 0, stream>>>(qbf, kbf, vtb, maskp, abf);
  proj_gemm<<<dim3(DIM_ / 128, TOK_ / 128), 256, 0, stream>>>(abf, wpb, proj_b, out);
}

// Round 7
// 204.823 us; speedup vs baseline: 1.8270x; 1.8270x over previous
//
#include <hip/hip_runtime.h>
#include <cstdint>

#define DIM_ 768
#define H_ 6
#define HD_ 128
#define NB_ 4
#define SEQ_ 2048
#define TOK_ (NB_*SEQ_)
#define OUT3_ (3*DIM_)
#define L2E 1.4426950408889634f

typedef __bf16 bf16;
typedef __bf16 bf16x4 __attribute__((ext_vector_type(4)));
typedef __bf16 bf16x8 __attribute__((ext_vector_type(8)));
typedef float f32x4 __attribute__((ext_vector_type(4)));
typedef float f32x16 __attribute__((ext_vector_type(16)));
typedef unsigned int u32;
typedef u32 u32x4 __attribute__((ext_vector_type(4)));

__device__ __forceinline__ void gload16(const void* g, void* lds) {
  __builtin_amdgcn_global_load_lds((const __attribute__((address_space(1))) void*)g,
                                   (__attribute__((address_space(3))) void*)lds,
                                   16, 0, 0);
}

// ---------------- fp32 -> bf16 convert ----------------
__global__ void convert_kernel(const float* __restrict__ in, bf16* __restrict__ out, int n) {
  int i = (blockIdx.x * 256 + threadIdx.x) * 4;
  if (i >= n) return;
  float4 v = *reinterpret_cast<const float4*>(in + i);
  bf16x4 o = { (bf16)v.x, (bf16)v.y, (bf16)v.z, (bf16)v.w };
  *reinterpret_cast<bf16x4*>(out + i) = o;
}

// ---------------- mask kernel ----------------
__global__ void mask_kernel(const float* __restrict__ latency,
                            const float* __restrict__ rw,
                            const float* __restrict__ rb,
                            const float* __restrict__ g1,
                            const float* __restrict__ g2,
                            float* __restrict__ mask6) {
  int i = threadIdx.x;
  if (i < 6) {
    int j = (i < 4) ? 0 : (i - 3);
    float logit = rw[j] * latency[0] + rb[j];
    float z = (logit + g1[j] - g2[j]) / 5.0f;
    float ys = 1.0f / (1.0f + expf(-z));
    float yh = ys > 0.5f ? 1.0f : 0.0f;
    mask6[i] = (yh - ys) + ys;
  }
}

// Fragment-major layouts (elements):
//  QF idx = (((bh*64 + n/32)*8 + d/16)*512) + ((d>>3&1)*32 + n%32)*8 + d%8
//  KF idx = ((((bh*32 + n/64)*2 + (n>>5&1))*8 + d/16)*512) + ((d>>3&1)*32 + n%32)*8 + d%8
//  VF idx = ((((bh*32 + n/64)*4 + (n>>4&3))*4 + d/32)*512) + ((n>>3&1)*32 + d%32)*8 + n%8

// ---------------- QKV GEMM (bf16 MFMA): qkv = x @ qkv_w^T + b ----------------
__global__ __launch_bounds__(256)
void qkv_gemm(const bf16* __restrict__ A, const bf16* __restrict__ W,
              const float* __restrict__ bias,
              bf16* __restrict__ q, bf16* __restrict__ k, bf16* __restrict__ vt) {
  __shared__ bf16 As[128 * 32];
  __shared__ bf16 Bs[128 * 32];
  const int tid = threadIdx.x;
  const int l = tid & 63, w = tid >> 6;
  const int lr = l & 15, lg = l >> 4;
  const int wm = w >> 1, wn = w & 1;
  const int tm = blockIdx.y * 128;
  const int on = blockIdx.x * 128;

  f32x4 acc[4][4];
#pragma unroll
  for (int i = 0; i < 4; ++i)
#pragma unroll
    for (int j = 0; j < 4; ++j) acc[i][j] = f32x4{0.f, 0.f, 0.f, 0.f};

  for (int k0 = 0; k0 < DIM_; k0 += 32) {
    __syncthreads();
#pragma unroll
    for (int u = 0; u < 2; ++u) {
      int row = w * 32 + u * 16 + (l >> 2);
      int cb = l & 3;
      gload16(A + (size_t)(tm + row) * DIM_ + k0 + cb * 8, As + (w * 32 + u * 16) * 32);
      gload16(W + (size_t)(on + row) * DIM_ + k0 + cb * 8, Bs + (w * 32 + u * 16) * 32);
    }
    __syncthreads();
    bf16x8 af[4], bfr[4];
#pragma unroll
    for (int i = 0; i < 4; ++i)
      af[i] = *reinterpret_cast<const bf16x8*>(As + (wm * 64 + i * 16 + lr) * 32 + lg * 8);
#pragma unroll
    for (int j = 0; j < 4; ++j)
      bfr[j] = *reinterpret_cast<const bf16x8*>(Bs + (wn * 64 + j * 16 + lr) * 32 + lg * 8);
#pragma unroll
    for (int i = 0; i < 4; ++i)
#pragma unroll
      for (int j = 0; j < 4; ++j)
        acc[i][j] = __builtin_amdgcn_mfma_f32_16x16x32_bf16(af[i], bfr[j], acc[i][j], 0, 0, 0);
  }

  if (on < 2 * DIM_) {
    const int s = on / DIM_;
    const float scale = 0.08838834764831845f * L2E;
#pragma unroll
    for (int i = 0; i < 4; ++i) {
      int t = tm + wm * 64 + i * 16 + lg * 4;
#pragma unroll
      for (int j = 0; j < 4; ++j) {
        int o = on + wn * 64 + j * 16 + lr;
        int rem = o - s * DIM_;
        int hh = rem >> 7, d = rem & 127;
        int kc = d >> 4, hi8 = (d >> 3) & 1, e = d & 7;
        float bia = bias[o];
#pragma unroll
        for (int r = 0; r < 4; ++r) {
          int tt = t + r;
          int bb = tt >> 11, n = tt & 2047;
          int bhh = bb * H_ + hh;
          float val = acc[i][j][r] + bia;
          if (s == 0) {
            size_t idx = ((((size_t)bhh * 64 + (n >> 5)) * 8 + kc) << 9) +
                         ((hi8 * 32 + (n & 31)) << 3) + e;
            q[idx] = (bf16)(val * scale);
          } else {
            size_t idx = (((((size_t)bhh * 32 + (n >> 6)) * 2 + ((n >> 5) & 1)) * 8 + kc) << 9) +
                         ((hi8 * 32 + (n & 31)) << 3) + e;
            k[idx] = (bf16)val;
          }
        }
      }
    }
  } else {
    // v: transpose 128x128 tile through LDS, write fragment-major VF (16B stores)
    const int hh = (on - 2 * DIM_) >> 7;
    const int bb = tm >> 11, n0 = tm & 2047;
    const int bhh = bb * H_ + hh;
    bf16(*Ts)[136] = reinterpret_cast<bf16(*)[136]>(As);
    for (int wc = 0; wc < 2; ++wc) {
#pragma unroll
      for (int j = 0; j < 4; ++j) {
        __syncthreads();
        if (wn == wc) {
          float bia = bias[on + wc * 64 + j * 16 + lr];
#pragma unroll
          for (int i = 0; i < 4; ++i) {
            bf16x4 pk;
#pragma unroll
            for (int r = 0; r < 4; ++r) pk[r] = (bf16)(acc[i][j][r] + bia);
            *reinterpret_cast<bf16x4*>(&Ts[lr][wm * 64 + i * 16 + lg * 4]) = pk;
          }
        }
        __syncthreads();
        int row = tid >> 4;
        int c8 = (tid & 15) * 8;
        bf16x8 v8 = *reinterpret_cast<const bf16x8*>(&Ts[row][c8]);
        int d = wc * 64 + j * 16 + row;
        int n = n0 + c8;
        size_t idx = (((((size_t)bhh * 32 + (n >> 6)) * 4 + ((n >> 4) & 3)) * 4 + (d >> 5)) << 9) +
                     ((((n >> 3) & 1) * 32 + (d & 31)) << 3);
        *reinterpret_cast<bf16x8*>(vt + idx) = v8;
      }
    }
  }
}

// ---------------- proj GEMM (bf16 MFMA): out = ab @ proj_w^T + b (fp32 out) ----------------
__global__ __launch_bounds__(256)
void proj_gemm(const bf16* __restrict__ A, const bf16* __restrict__ W,
               const float* __restrict__ bias, float* __restrict__ out) {
  __shared__ bf16 As[128 * 32];
  __shared__ bf16 Bs[128 * 32];
  const int tid = threadIdx.x;
  const int l = tid & 63, w = tid >> 6;
  const int lr = l & 15, lg = l >> 4;
  const int wm = w >> 1, wn = w & 1;
  const int tm = blockIdx.y * 128;
  const int on = blockIdx.x * 128;

  f32x4 acc[4][4];
#pragma unroll
  for (int i = 0; i < 4; ++i)
#pragma unroll
    for (int j = 0; j < 4; ++j) acc[i][j] = f32x4{0.f, 0.f, 0.f, 0.f};

  for (int k0 = 0; k0 < DIM_; k0 += 32) {
    __syncthreads();
#pragma unroll
    for (int u = 0; u < 2; ++u) {
      int row = w * 32 + u * 16 + (l >> 2);
      int cb = l & 3;
      gload16(A + (size_t)(tm + row) * DIM_ + k0 + cb * 8, As + (w * 32 + u * 16) * 32);
      gload16(W + (size_t)(on + row) * DIM_ + k0 + cb * 8, Bs + (w * 32 + u * 16) * 32);
    }
    __syncthreads();
    bf16x8 af[4], bfr[4];
#pragma unroll
    for (int i = 0; i < 4; ++i)
      af[i] = *reinterpret_cast<const bf16x8*>(As + (wm * 64 + i * 16 + lr) * 32 + lg * 8);
#pragma unroll
    for (int j = 0; j < 4; ++j)
      bfr[j] = *reinterpret_cast<const bf16x8*>(Bs + (wn * 64 + j * 16 + lr) * 32 + lg * 8);
#pragma unroll
    for (int i = 0; i < 4; ++i)
#pragma unroll
      for (int j = 0; j < 4; ++j)
        acc[i][j] = __builtin_amdgcn_mfma_f32_16x16x32_bf16(af[i], bfr[j], acc[i][j], 0, 0, 0);
  }

#pragma unroll
  for (int i = 0; i < 4; ++i) {
#pragma unroll
    for (int j = 0; j < 4; ++j) {
      int o = on + wn * 64 + j * 16 + lr;
      float bia = bias[o];
#pragma unroll
      for (int r = 0; r < 4; ++r) {
        int t = tm + wm * 64 + i * 16 + lg * 4 + r;
        out[(size_t)t * DIM_ + o] = acc[i][j][r] + bia;
      }
    }
  }
}

// ---------------- flash attention, 32x32x16 MFMA, fragment-major direct loads ----------
// 1 wave per block, QBLK=32, KVBLK=64; all loads 16B/lane fully coalesced, L2-resident.
// grid = 24 bh x 64 qtiles = 1536 blocks = 6 per CU.
__global__ __launch_bounds__(64)
void attn_kernel(const bf16* __restrict__ qf_g, const bf16* __restrict__ kf_g,
                 const bf16* __restrict__ vf_g, const float* __restrict__ mask6,
                 bf16* __restrict__ ab) {
  const int l = threadIdx.x & 63;
  const int kl = l & 31;
  const int hi = l >> 5;
  const int bid = blockIdx.x;
  const int bh = bid % 24;         // all q-tiles of a head on one XCD class
  const int qt = bid / 24;
  const int h = bh % H_;
  const int b = bh / H_;
  const int q0 = qt * 32;
  const int loff = l * 8;

  const bf16* qq = qf_g + (((size_t)bh * 64 + qt) * 8) * 512;
  const bf16* kq = kf_g + ((size_t)bh * 32) * 8192;   // per-jt stride 2*8*512
  const bf16* vq = vf_g + ((size_t)bh * 32) * 8192;   // per-jt stride 4*4*512

  // Q fragments (coalesced)
  bf16x8 qf[8];
#pragma unroll
  for (int kc = 0; kc < 8; ++kc)
    qf[kc] = *reinterpret_cast<const bf16x8*>(qq + kc * 512 + loff);

  f32x16 oacc[4];
#pragma unroll
  for (int df = 0; df < 4; ++df)
#pragma unroll
    for (int r = 0; r < 16; ++r) oacc[df][r] = 0.f;
  float m_lane = -3.0e38f;   // running max for q-row = kl (log2 units)
  float lsum = 0.f;          // per-half-wave partial row sum

  // preload K(jt=0): kreg[kf*8+kc]
  bf16x8 kreg[16];
#pragma unroll
  for (int f = 0; f < 16; ++f)
    kreg[f] = *reinterpret_cast<const bf16x8*>(kq + f * 512 + loff);

#pragma unroll 2
  for (int jt = 0; jt < 32; ++jt) {
    const bf16* vb = vq + (size_t)jt * 8192;
    // V ks=0,1 issued early (consumed after softmax)
    bf16x8 v01[8];
#pragma unroll
    for (int f = 0; f < 8; ++f)
      v01[f] = *reinterpret_cast<const bf16x8*>(vb + f * 512 + loff);

    // S^T = K Q^T
    f32x16 sacc[2];
#pragma unroll
    for (int kf = 0; kf < 2; ++kf)
#pragma unroll
      for (int r = 0; r < 16; ++r) sacc[kf][r] = 0.f;
    __builtin_amdgcn_s_setprio(1);
#pragma unroll
    for (int kc = 0; kc < 8; ++kc)
      sacc[0] = __builtin_amdgcn_mfma_f32_32x32x16_bf16(kreg[kc], qf[kc], sacc[0], 0, 0, 0);
#pragma unroll
    for (int kc = 0; kc < 8; ++kc)
      sacc[1] = __builtin_amdgcn_mfma_f32_32x32x16_bf16(kreg[8 + kc], qf[kc], sacc[1], 0, 0, 0);
    __builtin_amdgcn_s_setprio(0);

    // prefetch K(jt+1) (kreg dead after QK)
    const bf16* kb = kq + (size_t)((jt + 1) & 31) * 8192;
#pragma unroll
    for (int f = 0; f < 16; ++f)
      kreg[f] = *reinterpret_cast<const bf16x8*>(kb + f * 512 + loff);

    // lane-local online softmax for q-row = kl
    float t = sacc[0][0];
#pragma unroll
    for (int kf = 0; kf < 2; ++kf)
#pragma unroll
      for (int r = 0; r < 16; ++r) t = fmaxf(t, sacc[kf][r]);
    t = fmaxf(t, __shfl_xor(t, 32));
    bool need = t > m_lane + 8.0f;  // defer-max (P bounded by 2^8)
    if (__ballot(need) != 0ull) {
      float nm = fmaxf(m_lane, t);
      float c = exp2f(m_lane - nm);
      m_lane = nm;
      lsum *= c;
#pragma unroll
      for (int r = 0; r < 16; ++r) {
        float cr = __shfl(c, (r & 3) + 8 * (r >> 2) + 4 * hi);
#pragma unroll
        for (int df = 0; df < 4; ++df) oacc[df][r] *= cr;
      }
    }

    // P = exp2(S - m) -> bf16 pairs
    u32 pp[2][8];
#pragma unroll
    for (int kf = 0; kf < 2; ++kf)
#pragma unroll
      for (int m = 0; m < 8; ++m) {
        float e0 = exp2f(sacc[kf][2 * m] - m_lane);
        float e1 = exp2f(sacc[kf][2 * m + 1] - m_lane);
        lsum += e0 + e1;
        union { u32 u; bf16 hh2[2]; } pk;
        pk.hh2[0] = (bf16)e0; pk.hh2[1] = (bf16)e1;
        pp[kf][m] = pk.u;
      }

    // A-fragments for PV via permlane32_swap
    u32x4 afv[4];
#pragma unroll
    for (int ks = 0; ks < 4; ++ks) {
      int f = ks >> 1, k2 = ks & 1;
#pragma unroll
      for (int i = 0; i < 2; ++i) {
        u32 a = pp[f][4 * k2 + i];
        u32 b2 = pp[f][4 * k2 + 2 + i];
        asm volatile("v_permlane32_swap_b32 %0, %1" : "+v"(a), "+v"(b2));
        afv[ks][i] = a;
        afv[ks][2 + i] = b2;
      }
    }

    // V ks=2,3
    bf16x8 v23[8];
#pragma unroll
    for (int f = 0; f < 8; ++f)
      v23[f] = *reinterpret_cast<const bf16x8*>(vb + (8 + f) * 512 + loff);

    // PV: oacc[q][d] += P[q][key] V[key][d]
    __builtin_amdgcn_s_setprio(1);
#pragma unroll
    for (int ks = 0; ks < 2; ++ks) {
      bf16x8 pa = __builtin_bit_cast(bf16x8, afv[ks]);
#pragma unroll
      for (int df = 0; df < 4; ++df)
        oacc[df] = __builtin_amdgcn_mfma_f32_32x32x16_bf16(pa, v01[ks * 4 + df], oacc[df], 0, 0, 0);
    }
#pragma unroll
    for (int ks = 0; ks < 2; ++ks) {
      bf16x8 pa = __builtin_bit_cast(bf16x8, afv[2 + ks]);
#pragma unroll
      for (int df = 0; df < 4; ++df)
        oacc[df] = __builtin_amdgcn_mfma_f32_32x32x16_bf16(pa, v23[ks * 4 + df], oacc[df], 0, 0, 0);
    }
    __builtin_amdgcn_s_setprio(0);
  }

  // epilogue: merge half-wave sums, normalize, head mask, write bf16 [t][c]
  float lt = lsum + __shfl_xor(lsum, 32);
  float hm = mask6[h];
  float inv_l = hm / lt;           // valid for q-row = kl at this lane
#pragma unroll
  for (int r = 0; r < 16; ++r) {
    int qloc = (r & 3) + 8 * (r >> 2) + 4 * hi;
    float invr = __shfl(inv_l, qloc);
    int n = q0 + qloc;
#pragma unroll
    for (int df = 0; df < 4; ++df) {
      int d = df * 32 + kl;
      ab[((size_t)b * SEQ_ + n) * DIM_ + h * HD_ + d] = (bf16)(oacc[df][r] * invr);
    }
  }
}

extern "C" void kernel_launch(void* const* d_in, const int* in_sizes, int n_in,
                              void* d_out, int out_size, void* d_ws, size_t ws_size,
                              hipStream_t stream) {
  const float* x        = (const float*)d_in[0];
  const float* latency  = (const float*)d_in[1];
  const float* qkv_w    = (const float*)d_in[2];
  const float* qkv_b    = (const float*)d_in[3];
  const float* proj_w   = (const float*)d_in[4];
  const float* proj_b   = (const float*)d_in[5];
  const float* router_w = (const float*)d_in[6];
  const float* router_b = (const float*)d_in[7];
  const float* g1       = (const float*)d_in[8];
  const float* g2       = (const float*)d_in[9];
  float* out = (float*)d_out;

  const size_t N_X  = (size_t)TOK_ * DIM_;
  const size_t N_WQ = (size_t)OUT3_ * DIM_;
  const size_t N_WP = (size_t)DIM_ * DIM_;
  const size_t N_P  = (size_t)NB_ * H_ * SEQ_ * HD_;

  float* maskp = (float*)d_ws;
  bf16* xb  = (bf16*)((char*)d_ws + 256);
  bf16* wqb = xb + N_X;
  bf16* wpb = wqb + N_WQ;
  bf16* qbf = wpb + N_WP;
  bf16* kbf = qbf + N_P;
  bf16* vtb = kbf + N_P;
  bf16* abf = vtb + N_P;

  size_t need = 256 + 2 * (N_X + N_WQ + N_WP + 4 * N_P);
  if (ws_size < need) return;

  convert_kernel<<<(int)(N_X / 1024), 256, 0, stream>>>(x, xb, (int)N_X);
  convert_kernel<<<(int)(N_WQ / 1024), 256, 0, stream>>>(qkv_w, wqb, (int)N_WQ);
  convert_kernel<<<(int)(N_WP / 1024), 256, 0, stream>>>(proj_w, wpb, (int)N_WP);
  mask_kernel<<<1, 64, 0, stream>>>(latency, router_w, router_b, g1, g2, maskp);

  qkv_gemm<<<dim3(OUT3_ / 128, TOK_ / 128), 256, 0, stream>>>(xb, wqb, qkv_b, qbf, kbf, vtb);
  attn_kernel<<<dim3(24 * (SEQ_ / 32)), 64, 0, stream>>>(qbf, kbf, vtb, maskp, abf);
  proj_gemm<<<dim3(DIM_ / 128, TOK_ / 128), 256, 0, stream>>>(abf, wpb, proj_b, out);
}

// Round 8
// 197.191 us; speedup vs baseline: 1.8977x; 1.0387x over previous
//
#include <hip/hip_runtime.h>
#include <cstdint>

#define DIM_ 768
#define H_ 6
#define HD_ 128
#define NB_ 4
#define SEQ_ 2048
#define TOK_ (NB_*SEQ_)
#define OUT3_ (3*DIM_)
#define L2E 1.4426950408889634f

typedef __bf16 bf16;
typedef __bf16 bf16x4 __attribute__((ext_vector_type(4)));
typedef __bf16 bf16x8 __attribute__((ext_vector_type(8)));
typedef float f32x4 __attribute__((ext_vector_type(4)));
typedef float f32x16 __attribute__((ext_vector_type(16)));
typedef unsigned int u32;
typedef u32 u32x4 __attribute__((ext_vector_type(4)));

__device__ __forceinline__ void gload16(const void* g, void* lds) {
  __builtin_amdgcn_global_load_lds((const __attribute__((address_space(1))) void*)g,
                                   (__attribute__((address_space(3))) void*)lds,
                                   16, 0, 0);
}

// ---------------- fp32 -> bf16 convert ----------------
__global__ void convert_kernel(const float* __restrict__ in, bf16* __restrict__ out, int n) {
  int i = (blockIdx.x * 256 + threadIdx.x) * 4;
  if (i >= n) return;
  float4 v = *reinterpret_cast<const float4*>(in + i);
  bf16x4 o = { (bf16)v.x, (bf16)v.y, (bf16)v.z, (bf16)v.w };
  *reinterpret_cast<bf16x4*>(out + i) = o;
}

// ---------------- mask kernel ----------------
__global__ void mask_kernel(const float* __restrict__ latency,
                            const float* __restrict__ rw,
                            const float* __restrict__ rb,
                            const float* __restrict__ g1,
                            const float* __restrict__ g2,
                            float* __restrict__ mask6) {
  int i = threadIdx.x;
  if (i < 6) {
    int j = (i < 4) ? 0 : (i - 3);
    float logit = rw[j] * latency[0] + rb[j];
    float z = (logit + g1[j] - g2[j]) / 5.0f;
    float ys = 1.0f / (1.0f + expf(-z));
    float yh = ys > 0.5f ? 1.0f : 0.0f;
    mask6[i] = (yh - ys) + ys;
  }
}

// Fragment-major layouts (elements):
//  QF idx = (((bh*64 + n/32)*8 + kc)*512) + ((d>>3&1)*32 + n%32)*8 + d%8   [kc=d>>4]
//  KF idx = ((((bh*32 + n/64)*2 + (n>>5&1))*8 + kc)*512) + same-inner      -> 32-key tile jj: bh*262144 + jj*4096
//  VF idx = ((((bh*32 + n/64)*4 + (n>>4&3))*4 + d/32)*512) + ((n>>3&1)*32 + d%32)*8 + n%8

// ---------------- QKV GEMM (bf16 MFMA): qkv = x @ qkv_w^T + b ----------------
__global__ __launch_bounds__(256)
void qkv_gemm(const bf16* __restrict__ A, const bf16* __restrict__ W,
              const float* __restrict__ bias,
              bf16* __restrict__ q, bf16* __restrict__ k, bf16* __restrict__ vt) {
  __shared__ bf16 As[128 * 32];
  __shared__ bf16 Bs[128 * 32];
  __shared__ bf16 FragS[8192];   // 16 KB fragment-staging for q/k epilogue
  const int tid = threadIdx.x;
  const int l = tid & 63, w = tid >> 6;
  const int lr = l & 15, lg = l >> 4;
  const int wm = w >> 1, wn = w & 1;
  const int tm = blockIdx.y * 128;
  const int on = blockIdx.x * 128;

  f32x4 acc[4][4];
#pragma unroll
  for (int i = 0; i < 4; ++i)
#pragma unroll
    for (int j = 0; j < 4; ++j) acc[i][j] = f32x4{0.f, 0.f, 0.f, 0.f};

  for (int k0 = 0; k0 < DIM_; k0 += 32) {
    __syncthreads();
#pragma unroll
    for (int u = 0; u < 2; ++u) {
      int row = w * 32 + u * 16 + (l >> 2);
      int cb = l & 3;
      gload16(A + (size_t)(tm + row) * DIM_ + k0 + cb * 8, As + (w * 32 + u * 16) * 32);
      gload16(W + (size_t)(on + row) * DIM_ + k0 + cb * 8, Bs + (w * 32 + u * 16) * 32);
    }
    __syncthreads();
    bf16x8 af[4], bfr[4];
#pragma unroll
    for (int i = 0; i < 4; ++i)
      af[i] = *reinterpret_cast<const bf16x8*>(As + (wm * 64 + i * 16 + lr) * 32 + lg * 8);
#pragma unroll
    for (int j = 0; j < 4; ++j)
      bfr[j] = *reinterpret_cast<const bf16x8*>(Bs + (wn * 64 + j * 16 + lr) * 32 + lg * 8);
#pragma unroll
    for (int i = 0; i < 4; ++i)
#pragma unroll
      for (int j = 0; j < 4; ++j)
        acc[i][j] = __builtin_amdgcn_mfma_f32_16x16x32_bf16(af[i], bfr[j], acc[i][j], 0, 0, 0);
  }

  if (on < 2 * DIM_) {
    // q/k: build fragment-major 64-row tiles in LDS, store 16B-coalesced
    const int s = on / DIM_;
    const float scale = 0.08838834764831845f * L2E;
    const int n0 = tm & 2047;
    const int bb = tm >> 11;
    const int hh = (on - s * DIM_) >> 7;
    const int bhh = bb * H_ + hh;
    bf16* dstbase = (s == 0) ? q : k;
    for (int pass = 0; pass < 2; ++pass) {
      __syncthreads();
      if (wm == pass) {
#pragma unroll
        for (int i = 0; i < 4; ++i) {
#pragma unroll
          for (int j = 0; j < 4; ++j) {
            int dd = wn * 64 + j * 16 + lr;
            int kc = dd >> 4, hi8 = (dd >> 3) & 1, e = dd & 7;
            float bia = bias[on + dd];
#pragma unroll
            for (int r = 0; r < 4; ++r) {
              int nl = i * 16 + lg * 4 + r;          // 0..63
              float val = acc[i][j][r] + bia;
              if (s == 0) val *= scale;
              FragS[(((nl >> 5) * 8 + kc) << 9) + ((hi8 * 32 + (nl & 31)) << 3) + e] = (bf16)val;
            }
          }
        }
      }
      __syncthreads();
      size_t base = ((size_t)bhh * 64 + (n0 >> 5) + pass * 2) * 4096;
#pragma unroll
      for (int r8 = 0; r8 < 4; ++r8) {
        bf16x8 v8 = *reinterpret_cast<const bf16x8*>(FragS + r8 * 2048 + tid * 8);
        *reinterpret_cast<bf16x8*>(dstbase + base + r8 * 2048 + tid * 8) = v8;
      }
    }
  } else {
    // v: transpose 128x128 tile through LDS, write fragment-major VF (16B stores)
    const int hh = (on - 2 * DIM_) >> 7;
    const int bb = tm >> 11, n0 = tm & 2047;
    const int bhh = bb * H_ + hh;
    bf16(*Ts)[136] = reinterpret_cast<bf16(*)[136]>(As);
    for (int wc = 0; wc < 2; ++wc) {
#pragma unroll
      for (int j = 0; j < 4; ++j) {
        __syncthreads();
        if (wn == wc) {
          float bia = bias[on + wc * 64 + j * 16 + lr];
#pragma unroll
          for (int i = 0; i < 4; ++i) {
            bf16x4 pk;
#pragma unroll
            for (int r = 0; r < 4; ++r) pk[r] = (bf16)(acc[i][j][r] + bia);
            *reinterpret_cast<bf16x4*>(&Ts[lr][wm * 64 + i * 16 + lg * 4]) = pk;
          }
        }
        __syncthreads();
        int row = tid >> 4;
        int c8 = (tid & 15) * 8;
        bf16x8 v8 = *reinterpret_cast<const bf16x8*>(&Ts[row][c8]);
        int d = wc * 64 + j * 16 + row;
        int n = n0 + c8;
        size_t idx = (((((size_t)bhh * 32 + (n >> 6)) * 4 + ((n >> 4) & 3)) * 4 + (d >> 5)) << 9) +
                     ((((n >> 3) & 1) * 32 + (d & 31)) << 3);
        *reinterpret_cast<bf16x8*>(vt + idx) = v8;
      }
    }
  }
}

// ---------------- proj GEMM (bf16 MFMA): out = ab @ proj_w^T + b (fp32 out) ----------------
__global__ __launch_bounds__(256)
void proj_gemm(const bf16* __restrict__ A, const bf16* __restrict__ W,
               const float* __restrict__ bias, float* __restrict__ out) {
  __shared__ bf16 As[128 * 32];
  __shared__ bf16 Bs[128 * 32];
  const int tid = threadIdx.x;
  const int l = tid & 63, w = tid >> 6;
  const int lr = l & 15, lg = l >> 4;
  const int wm = w >> 1, wn = w & 1;
  const int tm = blockIdx.y * 128;
  const int on = blockIdx.x * 128;

  f32x4 acc[4][4];
#pragma unroll
  for (int i = 0; i < 4; ++i)
#pragma unroll
    for (int j = 0; j < 4; ++j) acc[i][j] = f32x4{0.f, 0.f, 0.f, 0.f};

  for (int k0 = 0; k0 < DIM_; k0 += 32) {
    __syncthreads();
#pragma unroll
    for (int u = 0; u < 2; ++u) {
      int row = w * 32 + u * 16 + (l >> 2);
      int cb = l & 3;
      gload16(A + (size_t)(tm + row) * DIM_ + k0 + cb * 8, As + (w * 32 + u * 16) * 32);
      gload16(W + (size_t)(on + row) * DIM_ + k0 + cb * 8, Bs + (w * 32 + u * 16) * 32);
    }
    __syncthreads();
    bf16x8 af[4], bfr[4];
#pragma unroll
    for (int i = 0; i < 4; ++i)
      af[i] = *reinterpret_cast<const bf16x8*>(As + (wm * 64 + i * 16 + lr) * 32 + lg * 8);
#pragma unroll
    for (int j = 0; j < 4; ++j)
      bfr[j] = *reinterpret_cast<const bf16x8*>(Bs + (wn * 64 + j * 16 + lr) * 32 + lg * 8);
#pragma unroll
    for (int i = 0; i < 4; ++i)
#pragma unroll
      for (int j = 0; j < 4; ++j)
        acc[i][j] = __builtin_amdgcn_mfma_f32_16x16x32_bf16(af[i], bfr[j], acc[i][j], 0, 0, 0);
  }

#pragma unroll
  for (int i = 0; i < 4; ++i) {
#pragma unroll
    for (int j = 0; j < 4; ++j) {
      int o = on + wn * 64 + j * 16 + lr;
      float bia = bias[o];
#pragma unroll
      for (int r = 0; r < 4; ++r) {
        int t = tm + wm * 64 + i * 16 + lg * 4 + r;
        out[(size_t)t * DIM_ + o] = acc[i][j][r] + bia;
      }
    }
  }
}

// ---------------- flash attention, 32x32x16 MFMA, LDS-shared K/V, dbuf ----------------
// 2 waves/block (QBLK=64, 32 q-rows each), KVBLK=32; fragment-major K/V tiles are
// contiguous 8KB -> linear global_load_lds; all LDS reads = base + lane*16B.
// grid = 24 bh x 32 qtiles = 768 blocks = 3 per CU exactly.
__global__ __launch_bounds__(128)
void attn_kernel(const bf16* __restrict__ qf_g, const bf16* __restrict__ kf_g,
                 const bf16* __restrict__ vf_g, const float* __restrict__ mask6,
                 bf16* __restrict__ ab) {
  __shared__ bf16 KS[2][4096];   // 8KB per buf
  __shared__ bf16 VS[2][4096];

  const int tid = threadIdx.x;
  const int l = tid & 63;
  const int wq = tid >> 6;       // 2 waves, 32 q-rows each
  const int kl = l & 31;
  const int hi = l >> 5;
  const int bid = blockIdx.x;
  const int bh = bid % 24;       // all q-tiles of a head on one XCD class
  const int qt2 = bid / 24;      // 64-row q block
  const int h = bh % H_;
  const int b = bh / H_;
  const int q0 = qt2 * 64 + wq * 32;
  const int loff = l * 8;

  const bf16* qq = qf_g + (((size_t)bh * 64 + qt2 * 2 + wq) * 8) * 512;
  const bf16* kq = kf_g + (size_t)bh * 262144;
  const bf16* vq = vf_g + (size_t)bh * 262144;

  // Q fragments (coalesced, held all kernel)
  bf16x8 qf[8];
#pragma unroll
  for (int kc = 0; kc < 8; ++kc)
    qf[kc] = *reinterpret_cast<const bf16x8*>(qq + kc * 512 + loff);

  f32x16 oacc[4];
#pragma unroll
  for (int df = 0; df < 4; ++df)
#pragma unroll
    for (int r = 0; r < 16; ++r) oacc[df][r] = 0.f;
  float m_lane = -3.0e38f;   // running max for q-row = kl (log2 units)
  float lsum = 0.f;          // per-half-wave partial row sum

  auto STAGE = [&](int jj, int buf) {
    const bf16* kb = kq + (size_t)jj * 4096;
    const bf16* vb = vq + (size_t)jj * 4096;
#pragma unroll
    for (int u = 0; u < 4; ++u) {
      int c = wq * 4 + u;
      gload16(kb + c * 512 + loff, &KS[buf][c * 512]);
      gload16(vb + c * 512 + loff, &VS[buf][c * 512]);
    }
  };

  STAGE(0, 0);
  __syncthreads();

  for (int jj = 0; jj < 64; ++jj) {
    int cur = jj & 1;
    STAGE((jj + 1) & 63, cur ^ 1);   // prefetch next tile while computing this one

    const bf16* Kc = &KS[cur][0];
    const bf16* Vc = &VS[cur][0];

    // S^T = K Q^T : lane (q=kl, hi) holds S[key][q], key = (r&3)+8*(r>>2)+4*hi
    f32x16 sacc;
#pragma unroll
    for (int r = 0; r < 16; ++r) sacc[r] = 0.f;
    __builtin_amdgcn_s_setprio(1);
#pragma unroll
    for (int kc = 0; kc < 8; ++kc) {
      bf16x8 kfr = *reinterpret_cast<const bf16x8*>(Kc + kc * 512 + loff);
      sacc = __builtin_amdgcn_mfma_f32_32x32x16_bf16(kfr, qf[kc], sacc, 0, 0, 0);
    }
    __builtin_amdgcn_s_setprio(0);

    // lane-local online softmax for q-row = kl
    float t = sacc[0];
#pragma unroll
    for (int r = 1; r < 16; ++r) t = fmaxf(t, sacc[r]);
    t = fmaxf(t, __shfl_xor(t, 32));
    bool need = t > m_lane + 8.0f;  // defer-max (P bounded by 2^8)
    if (__ballot(need) != 0ull) {
      float nm = fmaxf(m_lane, t);
      float c = exp2f(m_lane - nm);
      m_lane = nm;
      lsum *= c;
#pragma unroll
      for (int r = 0; r < 16; ++r) {
        float cr = __shfl(c, (r & 3) + 8 * (r >> 2) + 4 * hi);
#pragma unroll
        for (int df = 0; df < 4; ++df) oacc[df][r] *= cr;
      }
    }

    // P = exp2(S - m) -> bf16 pairs
    u32 pp[8];
#pragma unroll
    for (int m = 0; m < 8; ++m) {
      float e0 = exp2f(sacc[2 * m] - m_lane);
      float e1 = exp2f(sacc[2 * m + 1] - m_lane);
      lsum += e0 + e1;
      union { u32 u; bf16 hh2[2]; } pk;
      pk.hh2[0] = (bf16)e0; pk.hh2[1] = (bf16)e1;
      pp[m] = pk.u;
    }

    // A-fragments for PV via permlane32_swap
    u32x4 afv[2];
#pragma unroll
    for (int ks = 0; ks < 2; ++ks) {
#pragma unroll
      for (int i = 0; i < 2; ++i) {
        u32 a = pp[4 * ks + i];
        u32 b2 = pp[4 * ks + 2 + i];
        asm volatile("v_permlane32_swap_b32 %0, %1" : "+v"(a), "+v"(b2));
        afv[ks][i] = a;
        afv[ks][2 + i] = b2;
      }
    }

    // PV: oacc[q][d] += P[q][key] V[key][d]
    __builtin_amdgcn_s_setprio(1);
#pragma unroll
    for (int ks = 0; ks < 2; ++ks) {
      bf16x8 pa = __builtin_bit_cast(bf16x8, afv[ks]);
#pragma unroll
      for (int df = 0; df < 4; ++df) {
        bf16x8 vfr = *reinterpret_cast<const bf16x8*>(Vc + (ks * 4 + df) * 512 + loff);
        oacc[df] = __builtin_amdgcn_mfma_f32_32x32x16_bf16(pa, vfr, oacc[df], 0, 0, 0);
      }
    }
    __builtin_amdgcn_s_setprio(0);

    __syncthreads();   // next tile staged (vmcnt drain) + all reads of cur done
  }

  // epilogue: merge half-wave sums, normalize, head mask, write bf16 [t][c]
  float lt = lsum + __shfl_xor(lsum, 32);
  float hm = mask6[h];
  float inv_l = hm / lt;           // valid for q-row = kl at this lane
#pragma unroll
  for (int r = 0; r < 16; ++r) {
    int qloc = (r & 3) + 8 * (r >> 2) + 4 * hi;
    float invr = __shfl(inv_l, qloc);
    int n = q0 + qloc;
#pragma unroll
    for (int df = 0; df < 4; ++df) {
      int d = df * 32 + kl;
      ab[((size_t)b * SEQ_ + n) * DIM_ + h * HD_ + d] = (bf16)(oacc[df][r] * invr);
    }
  }
}

extern "C" void kernel_launch(void* const* d_in, const int* in_sizes, int n_in,
                              void* d_out, int out_size, void* d_ws, size_t ws_size,
                              hipStream_t stream) {
  const float* x        = (const float*)d_in[0];
  const float* latency  = (const float*)d_in[1];
  const float* qkv_w    = (const float*)d_in[2];
  const float* qkv_b    = (const float*)d_in[3];
  const float* proj_w   = (const float*)d_in[4];
  const float* proj_b   = (const float*)d_in[5];
  const float* router_w = (const float*)d_in[6];
  const float* router_b = (const float*)d_in[7];
  const float* g1       = (const float*)d_in[8];
  const float* g2       = (const float*)d_in[9];
  float* out = (float*)d_out;

  const size_t N_X  = (size_t)TOK_ * DIM_;
  const size_t N_WQ = (size_t)OUT3_ * DIM_;
  const size_t N_WP = (size_t)DIM_ * DIM_;
  const size_t N_P  = (size_t)NB_ * H_ * SEQ_ * HD_;

  float* maskp = (float*)d_ws;
  bf16* xb  = (bf16*)((char*)d_ws + 256);
  bf16* wqb = xb + N_X;
  bf16* wpb = wqb + N_WQ;
  bf16* qbf = wpb + N_WP;
  bf16* kbf = qbf + N_P;
  bf16* vtb = kbf + N_P;
  bf16* abf = vtb + N_P;

  size_t need = 256 + 2 * (N_X + N_WQ + N_WP + 4 * N_P);
  if (ws_size < need) return;

  convert_kernel<<<(int)(N_X / 1024), 256, 0, stream>>>(x, xb, (int)N_X);
  convert_kernel<<<(int)(N_WQ / 1024), 256, 0, stream>>>(qkv_w, wqb, (int)N_WQ);
  convert_kernel<<<(int)(N_WP / 1024), 256, 0, stream>>>(proj_w, wpb, (int)N_WP);
  mask_kernel<<<1, 64, 0, stream>>>(latency, router_w, router_b, g1, g2, maskp);

  qkv_gemm<<<dim3(OUT3_ / 128, TOK_ / 128), 256, 0, stream>>>(xb, wqb, qkv_b, qbf, kbf, vtb);
  attn_kernel<<<dim3(24 * (SEQ_ / 64)), 128, 0, stream>>>(qbf, kbf, vtb, maskp, abf);
  proj_gemm<<<dim3(DIM_ / 128, TOK_ / 128), 256, 0, stream>>>(abf, wpb, proj_b, out);
}

// Round 9
// 195.644 us; speedup vs baseline: 1.9128x; 1.0079x over previous
//
#include <hip/hip_runtime.h>
#include <cstdint>

#define DIM_ 768
#define H_ 6
#define HD_ 128
#define NB_ 4
#define SEQ_ 2048
#define TOK_ (NB_*SEQ_)
#define OUT3_ (3*DIM_)
#define L2E 1.4426950408889634f

typedef __bf16 bf16;
typedef __bf16 bf16x4 __attribute__((ext_vector_type(4)));
typedef __bf16 bf16x8 __attribute__((ext_vector_type(8)));
typedef float f32x4 __attribute__((ext_vector_type(4)));
typedef float f32x16 __attribute__((ext_vector_type(16)));
typedef unsigned int u32;
typedef u32 u32x4 __attribute__((ext_vector_type(4)));

__device__ __forceinline__ void gload16(const void* g, void* lds) {
  __builtin_amdgcn_global_load_lds((const __attribute__((address_space(1))) void*)g,
                                   (__attribute__((address_space(3))) void*)lds,
                                   16, 0, 0);
}

// ---------------- fp32 -> bf16 convert ----------------
__global__ void convert_kernel(const float* __restrict__ in, bf16* __restrict__ out, int n) {
  int i = (blockIdx.x * 256 + threadIdx.x) * 4;
  if (i >= n) return;
  float4 v = *reinterpret_cast<const float4*>(in + i);
  bf16x4 o = { (bf16)v.x, (bf16)v.y, (bf16)v.z, (bf16)v.w };
  *reinterpret_cast<bf16x4*>(out + i) = o;
}

// ---------------- mask kernel ----------------
__global__ void mask_kernel(const float* __restrict__ latency,
                            const float* __restrict__ rw,
                            const float* __restrict__ rb,
                            const float* __restrict__ g1,
                            const float* __restrict__ g2,
                            float* __restrict__ mask6) {
  int i = threadIdx.x;
  if (i < 6) {
    int j = (i < 4) ? 0 : (i - 3);
    float logit = rw[j] * latency[0] + rb[j];
    float z = (logit + g1[j] - g2[j]) / 5.0f;
    float ys = 1.0f / (1.0f + expf(-z));
    float yh = ys > 0.5f ? 1.0f : 0.0f;
    mask6[i] = (yh - ys) + ys;   // exactly 0.0f when gated off
  }
}

// Fragment-major layouts (elements):
//  QF idx = (((bh*64 + n/32)*8 + kc)*512) + ((d>>3&1)*32 + n%32)*8 + d%8   [kc=d>>4]
//  KF 32-key tile jj: contiguous 4096 elems at bh*262144 + jj*4096
//  VF 32-key tile jj: contiguous 4096 elems at bh*262144 + jj*4096

// ---------------- QKV GEMM (bf16 MFMA): qkv = x @ qkv_w^T + b ----------------
__global__ __launch_bounds__(256)
void qkv_gemm(const bf16* __restrict__ A, const bf16* __restrict__ W,
              const float* __restrict__ bias,
              bf16* __restrict__ q, bf16* __restrict__ k, bf16* __restrict__ vt) {
  __shared__ bf16 As[128 * 32];
  __shared__ bf16 Bs[128 * 32];
  __shared__ bf16 FragS[8192];   // 16 KB fragment-staging for q/k epilogue
  const int tid = threadIdx.x;
  const int l = tid & 63, w = tid >> 6;
  const int lr = l & 15, lg = l >> 4;
  const int wm = w >> 1, wn = w & 1;
  const int tm = blockIdx.y * 128;
  const int on = blockIdx.x * 128;

  f32x4 acc[4][4];
#pragma unroll
  for (int i = 0; i < 4; ++i)
#pragma unroll
    for (int j = 0; j < 4; ++j) acc[i][j] = f32x4{0.f, 0.f, 0.f, 0.f};

  for (int k0 = 0; k0 < DIM_; k0 += 32) {
    __syncthreads();
#pragma unroll
    for (int u = 0; u < 2; ++u) {
      int row = w * 32 + u * 16 + (l >> 2);
      int cb = l & 3;
      gload16(A + (size_t)(tm + row) * DIM_ + k0 + cb * 8, As + (w * 32 + u * 16) * 32);
      gload16(W + (size_t)(on + row) * DIM_ + k0 + cb * 8, Bs + (w * 32 + u * 16) * 32);
    }
    __syncthreads();
    bf16x8 af[4], bfr[4];
#pragma unroll
    for (int i = 0; i < 4; ++i)
      af[i] = *reinterpret_cast<const bf16x8*>(As + (wm * 64 + i * 16 + lr) * 32 + lg * 8);
#pragma unroll
    for (int j = 0; j < 4; ++j)
      bfr[j] = *reinterpret_cast<const bf16x8*>(Bs + (wn * 64 + j * 16 + lr) * 32 + lg * 8);
#pragma unroll
    for (int i = 0; i < 4; ++i)
#pragma unroll
      for (int j = 0; j < 4; ++j)
        acc[i][j] = __builtin_amdgcn_mfma_f32_16x16x32_bf16(af[i], bfr[j], acc[i][j], 0, 0, 0);
  }

  if (on < 2 * DIM_) {
    // q/k: build fragment-major 64-row tiles in LDS, store 16B-coalesced
    const int s = on / DIM_;
    const float scale = 0.08838834764831845f * L2E;
    const int n0 = tm & 2047;
    const int bb = tm >> 11;
    const int hh = (on - s * DIM_) >> 7;
    const int bhh = bb * H_ + hh;
    bf16* dstbase = (s == 0) ? q : k;
    for (int pass = 0; pass < 2; ++pass) {
      __syncthreads();
      if (wm == pass) {
#pragma unroll
        for (int i = 0; i < 4; ++i) {
#pragma unroll
          for (int j = 0; j < 4; ++j) {
            int dd = wn * 64 + j * 16 + lr;
            int kc = dd >> 4, hi8 = (dd >> 3) & 1, e = dd & 7;
            float bia = bias[on + dd];
#pragma unroll
            for (int r = 0; r < 4; ++r) {
              int nl = i * 16 + lg * 4 + r;          // 0..63
              float val = acc[i][j][r] + bia;
              if (s == 0) val *= scale;
              FragS[(((nl >> 5) * 8 + kc) << 9) + ((hi8 * 32 + (nl & 31)) << 3) + e] = (bf16)val;
            }
          }
        }
      }
      __syncthreads();
      size_t base = ((size_t)bhh * 64 + (n0 >> 5) + pass * 2) * 4096;
#pragma unroll
      for (int r8 = 0; r8 < 4; ++r8) {
        bf16x8 v8 = *reinterpret_cast<const bf16x8*>(FragS + r8 * 2048 + tid * 8);
        *reinterpret_cast<bf16x8*>(dstbase + base + r8 * 2048 + tid * 8) = v8;
      }
    }
  } else {
    // v: transpose 128x128 tile through LDS, write fragment-major VF (16B stores)
    const int hh = (on - 2 * DIM_) >> 7;
    const int bb = tm >> 11, n0 = tm & 2047;
    const int bhh = bb * H_ + hh;
    bf16(*Ts)[136] = reinterpret_cast<bf16(*)[136]>(As);
    for (int wc = 0; wc < 2; ++wc) {
#pragma unroll
      for (int j = 0; j < 4; ++j) {
        __syncthreads();
        if (wn == wc) {
          float bia = bias[on + wc * 64 + j * 16 + lr];
#pragma unroll
          for (int i = 0; i < 4; ++i) {
            bf16x4 pk;
#pragma unroll
            for (int r = 0; r < 4; ++r) pk[r] = (bf16)(acc[i][j][r] + bia);
            *reinterpret_cast<bf16x4*>(&Ts[lr][wm * 64 + i * 16 + lg * 4]) = pk;
          }
        }
        __syncthreads();
        int row = tid >> 4;
        int c8 = (tid & 15) * 8;
        bf16x8 v8 = *reinterpret_cast<const bf16x8*>(&Ts[row][c8]);
        int d = wc * 64 + j * 16 + row;
        int n = n0 + c8;
        size_t idx = (((((size_t)bhh * 32 + (n >> 6)) * 4 + ((n >> 4) & 3)) * 4 + (d >> 5)) << 9) +
                     ((((n >> 3) & 1) * 32 + (d & 31)) << 3);
        *reinterpret_cast<bf16x8*>(vt + idx) = v8;
      }
    }
  }
}

// ---------------- proj GEMM (bf16 MFMA): out = ab @ proj_w^T + b (fp32 out) ----------------
__global__ __launch_bounds__(256)
void proj_gemm(const bf16* __restrict__ A, const bf16* __restrict__ W,
               const float* __restrict__ bias, float* __restrict__ out) {
  __shared__ bf16 As[128 * 32];
  __shared__ bf16 Bs[128 * 32];
  const int tid = threadIdx.x;
  const int l = tid & 63, w = tid >> 6;
  const int lr = l & 15, lg = l >> 4;
  const int wm = w >> 1, wn = w & 1;
  const int tm = blockIdx.y * 128;
  const int on = blockIdx.x * 128;

  f32x4 acc[4][4];
#pragma unroll
  for (int i = 0; i < 4; ++i)
#pragma unroll
    for (int j = 0; j < 4; ++j) acc[i][j] = f32x4{0.f, 0.f, 0.f, 0.f};

  for (int k0 = 0; k0 < DIM_; k0 += 32) {
    __syncthreads();
#pragma unroll
    for (int u = 0; u < 2; ++u) {
      int row = w * 32 + u * 16 + (l >> 2);
      int cb = l & 3;
      gload16(A + (size_t)(tm + row) * DIM_ + k0 + cb * 8, As + (w * 32 + u * 16) * 32);
      gload16(W + (size_t)(on + row) * DIM_ + k0 + cb * 8, Bs + (w * 32 + u * 16) * 32);
    }
    __syncthreads();
    bf16x8 af[4], bfr[4];
#pragma unroll
    for (int i = 0; i < 4; ++i)
      af[i] = *reinterpret_cast<const bf16x8*>(As + (wm * 64 + i * 16 + lr) * 32 + lg * 8);
#pragma unroll
    for (int j = 0; j < 4; ++j)
      bfr[j] = *reinterpret_cast<const bf16x8*>(Bs + (wn * 64 + j * 16 + lr) * 32 + lg * 8);
#pragma unroll
    for (int i = 0; i < 4; ++i)
#pragma unroll
      for (int j = 0; j < 4; ++j)
        acc[i][j] = __builtin_amdgcn_mfma_f32_16x16x32_bf16(af[i], bfr[j], acc[i][j], 0, 0, 0);
  }

#pragma unroll
  for (int i = 0; i < 4; ++i) {
#pragma unroll
    for (int j = 0; j < 4; ++j) {
      int o = on + wn * 64 + j * 16 + lr;
      float bia = bias[o];
#pragma unroll
      for (int r = 0; r < 4; ++r) {
        int t = tm + wm * 64 + i * 16 + lg * 4 + r;
        out[(size_t)t * DIM_ + o] = acc[i][j][r] + bia;
      }
    }
  }
}

// ---------------- flash attention, split-K in-block, 32x32x16 MFMA ----------------
// 4 waves/block: (half = key-half, qw = q-wave). QBLK=64 (2 q-waves x 32 rows),
// each wave covers 1024 keys; LDS merge at end. grid = 24 bh x 32 qt = 768 blocks
// = 3 blocks/CU = 12 waves/CU (3/SIMD). LDS 33 KB -> 4 blocks/CU cap. Masked
// heads (mask==0) exit early with a zero tile.
__global__ __launch_bounds__(256)
void attn_kernel(const bf16* __restrict__ qf_g, const bf16* __restrict__ kf_g,
                 const bf16* __restrict__ vf_g, const float* __restrict__ mask6,
                 bf16* __restrict__ ab) {
  __shared__ char smem[33280];   // [K0 8K][K1 8K][V0 8K][V1 8K][ml 512B]

  const int tid = threadIdx.x;
  const int l = tid & 63;
  const int w = tid >> 6;
  const int half = w >> 1, qw = w & 1;
  const int kl = l & 31, hi = l >> 5;
  const int bid = blockIdx.x;
  const int bh = bid % 24;       // all q-tiles of a head on one XCD class
  const int qt2 = bid / 24;
  const int h = bh % H_;
  const int b = bh / H_;
  const int q0 = qt2 * 64 + qw * 32;
  const int loff = l * 8;
  const float hm = mask6[h];

  if (hm == 0.0f) {
    // gated head: output tile is exactly zero
    bf16x8 z = __builtin_bit_cast(bf16x8, u32x4{0u, 0u, 0u, 0u});
    int row = tid >> 2, c0 = (tid & 3) * 32;
    bf16* dst = ab + ((size_t)b * SEQ_ + qt2 * 64 + row) * DIM_ + h * HD_ + c0;
#pragma unroll
    for (int u = 0; u < 4; ++u)
      *reinterpret_cast<bf16x8*>(dst + u * 8) = z;
    return;
  }

  bf16* KSh = (bf16*)(smem + half * 8192);
  bf16* VSh = (bf16*)(smem + 16384 + half * 8192);
  float* MLm = (float*)(smem + 32768);
  float* MLl = MLm + 64;

  const bf16* qq = qf_g + (((size_t)bh * 64 + qt2 * 2 + qw) * 8) * 512;
  const bf16* kq = kf_g + (size_t)bh * 262144;
  const bf16* vq = vf_g + (size_t)bh * 262144;

  // Q fragments (coalesced, held all kernel)
  bf16x8 qf[8];
#pragma unroll
  for (int kc = 0; kc < 8; ++kc)
    qf[kc] = *reinterpret_cast<const bf16x8*>(qq + kc * 512 + loff);

  f32x16 oacc[4];
#pragma unroll
  for (int df = 0; df < 4; ++df)
#pragma unroll
    for (int r = 0; r < 16; ++r) oacc[df][r] = 0.f;
  float m_lane = -3.0e38f;   // running max for q-row = kl (log2 units)
  float lsum = 0.f;          // per-half-wave partial row sum

  for (int it = 0; it < 32; ++it) {
    int jj = half * 32 + it;
    // stage this half's 32-key K/V tile (each wave does its 4+4 columns)
#pragma unroll
    for (int u = 0; u < 4; ++u) {
      int c = qw * 4 + u;
      gload16(kq + (size_t)jj * 4096 + c * 512 + loff, KSh + c * 512);
      gload16(vq + (size_t)jj * 4096 + c * 512 + loff, VSh + c * 512);
    }
    __syncthreads();   // vmcnt(0) drain: tile staged

    // S^T = K Q^T : lane (q=kl, hi) holds S[key][q]
    f32x16 sacc;
#pragma unroll
    for (int r = 0; r < 16; ++r) sacc[r] = 0.f;
    __builtin_amdgcn_s_setprio(1);
#pragma unroll
    for (int kc = 0; kc < 8; ++kc) {
      bf16x8 kfr = *reinterpret_cast<const bf16x8*>(KSh + kc * 512 + loff);
      sacc = __builtin_amdgcn_mfma_f32_32x32x16_bf16(kfr, qf[kc], sacc, 0, 0, 0);
    }
    __builtin_amdgcn_s_setprio(0);

    // lane-local online softmax for q-row = kl
    float t = sacc[0];
#pragma unroll
    for (int r = 1; r < 16; ++r) t = fmaxf(t, sacc[r]);
    t = fmaxf(t, __shfl_xor(t, 32));
    bool need = t > m_lane + 8.0f;  // defer-max (P bounded by 2^8)
    if (__ballot(need) != 0ull) {
      float nm = fmaxf(m_lane, t);
      float c = exp2f(m_lane - nm);
      m_lane = nm;
      lsum *= c;
#pragma unroll
      for (int r = 0; r < 16; ++r) {
        float cr = __shfl(c, (r & 3) + 8 * (r >> 2) + 4 * hi);
#pragma unroll
        for (int df = 0; df < 4; ++df) oacc[df][r] *= cr;
      }
    }

    // P = exp2(S - m) -> bf16 pairs
    u32 pp[8];
#pragma unroll
    for (int m = 0; m < 8; ++m) {
      float e0 = exp2f(sacc[2 * m] - m_lane);
      float e1 = exp2f(sacc[2 * m + 1] - m_lane);
      lsum += e0 + e1;
      union { u32 u; bf16 hh2[2]; } pk;
      pk.hh2[0] = (bf16)e0; pk.hh2[1] = (bf16)e1;
      pp[m] = pk.u;
    }

    // A-fragments for PV via permlane32_swap
    u32x4 afv[2];
#pragma unroll
    for (int ks = 0; ks < 2; ++ks) {
#pragma unroll
      for (int i = 0; i < 2; ++i) {
        u32 a = pp[4 * ks + i];
        u32 b2 = pp[4 * ks + 2 + i];
        asm volatile("v_permlane32_swap_b32 %0, %1" : "+v"(a), "+v"(b2));
        afv[ks][i] = a;
        afv[ks][2 + i] = b2;
      }
    }

    // PV: oacc[q][d] += P[q][key] V[key][d]
    __builtin_amdgcn_s_setprio(1);
#pragma unroll
    for (int ks = 0; ks < 2; ++ks) {
      bf16x8 pa = __builtin_bit_cast(bf16x8, afv[ks]);
#pragma unroll
      for (int df = 0; df < 4; ++df) {
        bf16x8 vfr = *reinterpret_cast<const bf16x8*>(VSh + (ks * 4 + df) * 512 + loff);
        oacc[df] = __builtin_amdgcn_mfma_f32_32x32x16_bf16(pa, vfr, oacc[df], 0, 0, 0);
      }
    }
    __builtin_amdgcn_s_setprio(0);

    __syncthreads();   // all reads done before next stage overwrites
  }

  float lt = lsum + __shfl_xor(lsum, 32);   // this half's l for q-row = kl

  // ---- split-K merge through LDS ----
  float* OM = (float*)smem;                 // 2 x 16KB, indexed by qw
  if (half == 1) {
#pragma unroll
    for (int r = 0; r < 16; ++r) {
      int qloc = (r & 3) + 8 * (r >> 2) + 4 * hi;
#pragma unroll
      for (int df = 0; df < 4; ++df)
        OM[qw * 4096 + qloc * 128 + df * 32 + kl] = oacc[df][r];
    }
    MLm[qw * 32 + kl] = m_lane;             // lanes hi=0/1 write same value
    MLl[qw * 32 + kl] = lt;
  }
  __syncthreads();
  if (half == 1) return;

  float m1 = MLm[qw * 32 + kl];
  float l1 = MLl[qw * 32 + kl];
  float M = fmaxf(m_lane, m1);
  float a0 = exp2f(m_lane - M), a1 = exp2f(m1 - M);
  float L = lt * a0 + l1 * a1;
  float s0 = a0 * hm / L, s1 = a1 * hm / L;   // per lane = q-row kl

#pragma unroll
  for (int r = 0; r < 16; ++r) {
    int qloc = (r & 3) + 8 * (r >> 2) + 4 * hi;
    float r0 = __shfl(s0, qloc);
    float r1 = __shfl(s1, qloc);
    int n = q0 + qloc;
#pragma unroll
    for (int df = 0; df < 4; ++df) {
      int d = df * 32 + kl;
      float o1 = OM[qw * 4096 + qloc * 128 + df * 32 + kl];
      ab[((size_t)b * SEQ_ + n) * DIM_ + h * HD_ + d] =
          (bf16)(oacc[df][r] * r0 + o1 * r1);
    }
  }
}

extern "C" void kernel_launch(void* const* d_in, const int* in_sizes, int n_in,
                              void* d_out, int out_size, void* d_ws, size_t ws_size,
                              hipStream_t stream) {
  const float* x        = (const float*)d_in[0];
  const float* latency  = (const float*)d_in[1];
  const float* qkv_w    = (const float*)d_in[2];
  const float* qkv_b    = (const float*)d_in[3];
  const float* proj_w   = (const float*)d_in[4];
  const float* proj_b   = (const float*)d_in[5];
  const float* router_w = (const float*)d_in[6];
  const float* router_b = (const float*)d_in[7];
  const float* g1       = (const float*)d_in[8];
  const float* g2       = (const float*)d_in[9];
  float* out = (float*)d_out;

  const size_t N_X  = (size_t)TOK_ * DIM_;
  const size_t N_WQ = (size_t)OUT3_ * DIM_;
  const size_t N_WP = (size_t)DIM_ * DIM_;
  const size_t N_P  = (size_t)NB_ * H_ * SEQ_ * HD_;

  float* maskp = (float*)d_ws;
  bf16* xb  = (bf16*)((char*)d_ws + 256);
  bf16* wqb = xb + N_X;
  bf16* wpb = wqb + N_WQ;
  bf16* qbf = wpb + N_WP;
  bf16* kbf = qbf + N_P;
  bf16* vtb = kbf + N_P;
  bf16* abf = vtb + N_P;

  size_t need = 256 + 2 * (N_X + N_WQ + N_WP + 4 * N_P);
  if (ws_size < need) return;

  convert_kernel<<<(int)(N_X / 1024), 256, 0, stream>>>(x, xb, (int)N_X);
  convert_kernel<<<(int)(N_WQ / 1024), 256, 0, stream>>>(qkv_w, wqb, (int)N_WQ);
  convert_kernel<<<(int)(N_WP / 1024), 256, 0, stream>>>(proj_w, wpb, (int)N_WP);
  mask_kernel<<<1, 64, 0, stream>>>(latency, router_w, router_b, g1, g2, maskp);

  qkv_gemm<<<dim3(OUT3_ / 128, TOK_ / 128), 256, 0, stream>>>(xb, wqb, qkv_b, qbf, kbf, vtb);
  attn_kernel<<<dim3(24 * (SEQ_ / 64)), 256, 0, stream>>>(qbf, kbf, vtb, maskp, abf);
  proj_gemm<<<dim3(DIM_ / 128, TOK_ / 128), 256, 0, stream>>>(abf, wpb, proj_b, out);
}